// Round 5
// baseline (134.975 us; speedup 1.0000x reference)
//
#include <hip/hip_runtime.h>
#include <stdint.h>
#include <float.h>

using u64 = unsigned long long;
typedef float v2f __attribute__((ext_vector_type(2)));

constexpr int B_ = 2;
constexpr int NC = 512;
constexpr int NF = 8192;
constexpr int MT = 8192;

constexpr int TPB = 256;
constexpr int RPB = 512;           // rows per block (2 per thread, packed v2f)
constexpr int CF  = 16;            // fine-rows j-chunks (512 j each)
constexpr int CFC = 8;             // fine-cols j-chunks (1024 j each)
constexpr int TAIL_BLOCKS = 196;   // 64 + 64 + 4 + 64

#define DEVINL __device__ __forceinline__

// ---------------------------------------------------------------------------
// prep: build float4 (x,y,z,xx) arrays so pairmin can fetch Q points with
// wave-uniform s_load (scalar pipe) — no LDS staging, no barriers.
// qq = (x*x + y*y) + z*z with contract(off): bit-identical to numpy fp32.
// ---------------------------------------------------------------------------
__global__ __launch_bounds__(TPB) void prep(
    const float* __restrict__ coarse, const float* __restrict__ fine,
    const float* __restrict__ tgt,
    float4* __restrict__ fine4, float4* __restrict__ tgt4,
    float4* __restrict__ coarse4, unsigned* __restrict__ counter)
{
#pragma clang fp contract(off)
    int g = blockIdx.x * TPB + threadIdx.x;
    if (g == 0) *counter = 0;
    if (g < B_ * NF) {
        const float* p = fine + (size_t)g * 3;
        float x = p[0], y = p[1], z = p[2];
        fine4[g] = make_float4(x, y, z, (x*x + y*y) + z*z);
        p = tgt + (size_t)g * 3;
        x = p[0]; y = p[1]; z = p[2];
        tgt4[g] = make_float4(x, y, z, (x*x + y*y) + z*z);
        if (g < B_ * NC) {
            p = coarse + (size_t)g * 3;
            x = p[0]; y = p[1]; z = p[2];
            coarse4[g] = make_float4(x, y, z, (x*x + y*y) + z*z);
        }
    }
}

// ---------------------------------------------------------------------------
// pairmin: RPB rows of P vs [j0, j0+jlen) of Qf. Per pair, bit-exact numpy:
//   d = max((xx (+) qq) (-) ((2x0)q0 (+) (2x1)q1 (+) (2x2)q2), 0)
// (power-of-2 prescale commutes with rounding => equals xx+qq-2*xy exactly).
// Q fetched via block-uniform float4 loads (-> s_load, SGPR operands),
// software-pipelined one group of 4 ahead. Two rows/thread packed as v2f.
// Partial results to per-chunk slots: no atomics, no sentinel init.
// ---------------------------------------------------------------------------
template<bool ARGMIN>
DEVINL void pairmin_body(const float* __restrict__ P, const float4* __restrict__ Qf,
                         int nP, int nQb, int b, int row_base, int j0, int jlen,
                         int chunk, int nRowsTot,
                         u64* __restrict__ outPack, unsigned* __restrict__ outVal)
{
#pragma clang fp contract(off)
    const int tid  = threadIdx.x;
    const int row0 = row_base + tid;
    const int row1 = row_base + tid + TPB;
    const float* p0 = P + ((size_t)b * nP + row0) * 3;
    const float* p1 = P + ((size_t)b * nP + row1) * 3;
    float a0 = p0[0], a1 = p0[1], a2 = p0[2];
    float e0 = p1[0], e1 = p1[1], e2 = p1[2];
    v2f tx0 = {2.0f * a0, 2.0f * e0};
    v2f tx1 = {2.0f * a1, 2.0f * e1};
    v2f tx2 = {2.0f * a2, 2.0f * e2};
    v2f txx = {(a0*a0 + a1*a1) + a2*a2, (e0*e0 + e1*e1) + e2*e2};
    v2f dbest = {FLT_MAX, FLT_MAX};
    const v2f vzero = {0.0f, 0.0f};
    int jb0 = 0, jb1 = 0;

    const float4* Q = Qf + (size_t)b * nQb;
    // prefetch group 0 (block-uniform addresses -> scalar loads)
    float4 c0 = Q[j0], c1 = Q[j0+1], c2 = Q[j0+2], c3 = Q[j0+3];

    for (int j = j0; j < j0 + jlen; j += 4) {
        // prefetch next group unconditionally (overrun stays inside ws — safe)
        float4 n0 = Q[j+4], n1 = Q[j+5], n2 = Q[j+6], n3 = Q[j+7];
        float4 qg[4] = {c0, c1, c2, c3};
        #pragma unroll
        for (int u = 0; u < 4; ++u) {
            float4 q = qg[u];
            v2f s  = (tx0 * q.x + tx1 * q.y) + tx2 * q.z;   // == 2*xy bitwise
            v2f tt = txx + q.w;
            v2f d  = tt - s;
            v2f dc = __builtin_elementwise_max(d, vzero);
            if (ARGMIN) {
                int jj = j + u;
                bool g0 = dc.x < dbest.x;    // strict: first index wins
                dbest.x = g0 ? dc.x : dbest.x;  jb0 = g0 ? jj : jb0;
                bool g1 = dc.y < dbest.y;
                dbest.y = g1 ? dc.y : dbest.y;  jb1 = g1 ? jj : jb1;
            } else {
                dbest = __builtin_elementwise_min(dbest, dc);
            }
        }
        c0 = n0; c1 = n1; c2 = n2; c3 = n3;
    }

    const size_t o0 = (size_t)chunk * nRowsTot + (size_t)b * nP;
    if (ARGMIN) {
        outPack[o0 + row0] = ((u64)__float_as_uint(dbest.x) << 32) | (unsigned)jb0;
        outPack[o0 + row1] = ((u64)__float_as_uint(dbest.y) << 32) | (unsigned)jb1;
    } else {
        outVal[o0 + row0] = __float_as_uint(dbest.x);
        outVal[o0 + row1] = __float_as_uint(dbest.y);
    }
}

// All four pairwise passes, one dispatch, 832 blocks, big blocks first.
//  [0,  256) fine-cols  : P=tgt,    Q=fine4,   8 chunks x 1024 j  (2 work units)
//  [256,768) fine-rows  : P=fine,   Q=tgt4,   16 chunks x 512 j, ARGMIN
//  [768,800) coarse-rows: P=coarse, Q=tgt4,   16 chunks x 512 j
//  [800,832) coarse-cols: P=tgt,    Q=coarse4, 1 chunk  x 512 j
__global__ __launch_bounds__(TPB, 8) void pairmin_all(
    const float* __restrict__ coarse, const float* __restrict__ fine,
    const float* __restrict__ tgt,
    const float4* __restrict__ fine4, const float4* __restrict__ tgt4,
    const float4* __restrict__ coarse4,
    u64* __restrict__ pfr, unsigned* __restrict__ pfc,
    unsigned* __restrict__ pcr, unsigned* __restrict__ pcc)
{
    const int bx = blockIdx.x;
    if (bx < 256) {
        int chunk = bx & 7, yb = (bx >> 3) & 15, b = bx >> 7;
        pairmin_body<false>(tgt, fine4, MT, NF, b, yb * RPB, chunk * 1024, 1024,
                            chunk, B_ * MT, nullptr, pfc);
    } else if (bx < 768) {
        int i = bx - 256;
        int chunk = i & 15, yb = (i >> 4) & 15, b = i >> 8;
        pairmin_body<true>(fine, tgt4, NF, MT, b, yb * RPB, chunk * 512, 512,
                           chunk, B_ * NF, pfr, nullptr);
    } else if (bx < 800) {
        int i = bx - 768;
        int chunk = i & 15, b = i >> 4;
        pairmin_body<false>(coarse, tgt4, NC, MT, b, 0, chunk * 512, 512,
                            chunk, B_ * NC, nullptr, pcr);
    } else {
        int i = bx - 800;
        int yb = i & 15, b = i >> 4;
        pairmin_body<false>(tgt, coarse4, MT, NC, b, yb * RPB, 0, 512,
                            0, B_ * MT, nullptr, pcc);
    }
}

// ---------------------------------------------------------------------------
// tail_all: everything after the pairwise passes, one dispatch.
//  [0,  64) fine-rows: reduce 16 u64 partials, gather, chamfer d1, ref/rot
//           stats, wedge volumes (LDS halo).
//  [64,128) fine-cols: reduce 8 value partials -> d2f
//  [128,132) coarse-rows: reduce 16 -> d1c
//  [132,196) coarse-cols: single partial -> d2c
// Per-block sums to bs[bx][16]; last-arriving block combines and writes out.
// ---------------------------------------------------------------------------
__global__ __launch_bounds__(TPB) void tail_all(
    const float* __restrict__ fine, const float* __restrict__ tgt,
    const u64* __restrict__ pfr, const unsigned* __restrict__ pfc,
    const unsigned* __restrict__ pcr, const unsigned* __restrict__ pcc,
    double* __restrict__ bs, unsigned* __restrict__ counter,
    float* __restrict__ out)
{
    __shared__ float sp[TPB + 2][3], yp[TPB + 2][3];
    __shared__ double redw[4][9];
    __shared__ double lred[4][13];
    __shared__ int lastflag;
    const int bx = blockIdx.x, tid = threadIdx.x;
    const int wave = tid >> 6, lane = tid & 63;

    double v_s = 0, v_d2f = 0, v_d1c = 0, v_d2c = 0, v_yd2 = 0, v_zs = 0, v_zt = 0;
    double vs = 0, vt = 0;
    int role_b = 0;

    if (bx < 64) {                              // ---- fine-rows ----
        const int base = bx * TPB;
        const int g = base + tid;
        const int b = base >> 13;  role_b = b;
        u64 best = pfr[g];
        #pragma unroll
        for (int c = 1; c < CF; ++c) {
            u64 p = pfr[(size_t)c * (B_ * NF) + g];
            best = p < best ? p : best;
        }
        float d1 = __uint_as_float((unsigned)(best >> 32));
        int idx  = (int)(best & 0xffffffffULL);
        float s = sqrtf(fmaxf(d1, 1e-12f));
        const float* y  = tgt  + ((size_t)b * MT + idx) * 3;
        const float* sr = fine + (size_t)g * 3;
        float y0 = y[0],  y1 = y[1],  y2 = y[2];
        float s0 = sr[0], s1 = sr[1], s2 = sr[2];
        yp[tid][0] = y0; yp[tid][1] = y1; yp[tid][2] = y2;
        sp[tid][0] = s0; sp[tid][1] = s1; sp[tid][2] = s2;
        const int base_b = base & (NF - 1);
        if (tid < 2 && base_b + TPB + tid < NF) {        // halo rows
            int g2 = base + TPB + tid;
            u64 b2 = pfr[g2];
            #pragma unroll
            for (int c = 1; c < CF; ++c) {
                u64 p = pfr[(size_t)c * (B_ * NF) + g2];
                b2 = p < b2 ? p : b2;
            }
            int i2 = (int)(b2 & 0xffffffffULL);
            const float* yh = tgt  + ((size_t)b * MT + i2) * 3;
            const float* sh = fine + (size_t)g2 * 3;
            #pragma unroll
            for (int k = 0; k < 3; ++k) { yp[TPB + tid][k] = yh[k]; sp[TPB + tid][k] = sh[k]; }
        }
        __syncthreads();
        v_s = s;
        float yd = s1 - y1;
        v_yd2 = (double)(yd * yd);
        v_zs  = (double)(s2 * s2);
        v_zt  = (double)(y2 * y2);
        int rb = base_b + tid;
        if (rb <= NF - 3) {          // same f32 exprs as the verified R3 kernel
            {
                const float* a = sp[tid]; const float* c = sp[tid+1]; const float* e = sp[tid+2];
                float c0 = a[1]*c[2] - a[2]*c[1];
                float c1 = a[2]*c[0] - a[0]*c[2];
                float c2 = a[0]*c[1] - a[1]*c[0];
                vs = (double)(c0*e[0] + c1*e[1] + c2*e[2]);
            }
            {
                const float* a = yp[tid]; const float* c = yp[tid+1]; const float* e = yp[tid+2];
                float c0 = a[1]*c[2] - a[2]*c[1];
                float c1 = a[2]*c[0] - a[0]*c[2];
                float c2 = a[0]*c[1] - a[1]*c[0];
                vt = (double)(c0*e[0] + c1*e[1] + c2*e[2]);
            }
        }
    } else if (bx < 128) {                      // ---- fine-cols ----
        const int g = (bx - 64) * TPB + tid;
        unsigned best = pfc[g];
        #pragma unroll
        for (int c = 1; c < CFC; ++c) best = min(best, pfc[(size_t)c * (B_ * MT) + g]);
        v_d2f = (double)sqrtf(fmaxf(__uint_as_float(best), 1e-12f));
    } else if (bx < 132) {                      // ---- coarse-rows ----
        const int g = (bx - 128) * TPB + tid;
        unsigned best = pcr[g];
        #pragma unroll
        for (int c = 1; c < 16; ++c) best = min(best, pcr[(size_t)c * (B_ * NC) + g]);
        v_d1c = (double)sqrtf(fmaxf(__uint_as_float(best), 1e-12f));
    } else {                                    // ---- coarse-cols ----
        const int g = (bx - 132) * TPB + tid;
        v_d2c = (double)sqrtf(fmaxf(__uint_as_float(pcc[g]), 1e-12f));
    }

    // block reduce 9 values
    double r9[9] = {v_s, v_d2f, v_d1c, v_d2c, v_yd2, v_zs, v_zt, vs, vt};
    for (int o = 32; o; o >>= 1) {
        #pragma unroll
        for (int k = 0; k < 9; ++k) r9[k] += __shfl_down(r9[k], o);
    }
    if (lane == 0) {
        #pragma unroll
        for (int k = 0; k < 9; ++k) redw[wave][k] = r9[k];
    }
    __syncthreads();
    if (tid == 0) {
        double t9[9];
        #pragma unroll
        for (int k = 0; k < 9; ++k)
            t9[k] = redw[0][k] + redw[1][k] + redw[2][k] + redw[3][k];
        double* o = bs + (size_t)bx * 16;
        #pragma unroll
        for (int k = 0; k < 16; ++k) o[k] = 0.0;
        o[0] = t9[0]; o[1] = t9[1]; o[2] = t9[2]; o[3] = t9[3]; o[4] = t9[4];
        o[5 + role_b]  = t9[5];   // zs
        o[7 + role_b]  = t9[6];   // zt
        o[9 + role_b]  = t9[7];   // vs
        o[11 + role_b] = t9[8];   // vt
        __threadfence();
        unsigned old = atomicAdd(counter, 1u);
        lastflag = (old == TAIL_BLOCKS - 1);
    }
    __syncthreads();
    if (!lastflag) return;

    // ---- final combine (last block only) ----
    __threadfence();
    double c13[13];
    if (tid < TAIL_BLOCKS) {
        const double* p = bs + (size_t)tid * 16;
        #pragma unroll
        for (int k = 0; k < 13; ++k) c13[k] = p[k];
    } else {
        #pragma unroll
        for (int k = 0; k < 13; ++k) c13[k] = 0.0;
    }
    for (int o = 32; o; o >>= 1) {
        #pragma unroll
        for (int k = 0; k < 13; ++k) c13[k] += __shfl_down(c13[k], o);
    }
    if (lane == 0) {
        #pragma unroll
        for (int k = 0; k < 13; ++k) lred[wave][k] = c13[k];
    }
    __syncthreads();
    if (tid == 0) {
        double S[13];
        #pragma unroll
        for (int k = 0; k < 13; ++k)
            S[k] = lred[0][k] + lred[1][k] + lred[2][k] + lred[3][k];
        double m_d1f = S[0] / (double)(B_ * NF);
        double m_d2f = S[1] / (double)(B_ * MT);
        double m_d1c = S[2] / (double)(B_ * NC);
        double m_d2c = S[3] / (double)(B_ * MT);
        double loss_align_fine   = 0.5 * (m_d1f + m_d2f);
        double loss_align_coarse = 0.5 * (m_d1c + m_d2c);
        double loss_ref = S[4] / (double)(B_ * NF);
        double loss_rot = 0.0, loss_geo = 0.0;
        for (int b = 0; b < B_; ++b) {
            double dn = sqrt(S[5 + b]) - sqrt(S[7 + b]);
            loss_rot += dn * dn;
            double dv = (S[9 + b] - S[11 + b]) / 6.0;
            loss_geo += dv * dv;
        }
        loss_rot /= (double)B_;
        loss_geo /= (double)B_;
        out[0] = (float)(loss_rot + loss_ref + loss_align_coarse + loss_align_fine + loss_geo);
    }
}

extern "C" void kernel_launch(void* const* d_in, const int* in_sizes, int n_in,
                              void* d_out, int out_size, void* d_ws, size_t ws_size,
                              hipStream_t stream)
{
    const float* src_coarse = (const float*)d_in[0];
    const float* src_fine   = (const float*)d_in[1];
    const float* tgt        = (const float*)d_in[2];
    float* out = (float*)d_out;
    char*  ws  = (char*)d_ws;

    // ws layout (bytes), everything written before read — no init needed:
    //   [0,        2097152)  u64 pfr[16][16384]   fine-rows (d,j) partials
    //   [2097152,  2621440)  u32 pfc[8][16384]    fine-cols value partials
    //   [2621440,  2686976)  u32 pcr[16][1024]    coarse-rows value partials
    //   [2686976,  2752512)  u32 pcc[1][16384]    coarse-cols value partials
    //   [2752512,  3014656)  float4 fine4[16384]
    //   [3014656,  3276800)  float4 tgt4[16384]
    //   [3276800,  3293184)  float4 coarse4[1024]
    //   [3293184,  3318272)  double bs[196][16]   per-tail-block sums
    //   [3318272,  3318276)  u32 counter          (zeroed by prep)
    u64*      pfr     = (u64*)(ws);
    unsigned* pfc     = (unsigned*)(ws + 2097152);
    unsigned* pcr     = (unsigned*)(ws + 2621440);
    unsigned* pcc     = (unsigned*)(ws + 2686976);
    float4*   fine4   = (float4*)(ws + 2752512);
    float4*   tgt4    = (float4*)(ws + 3014656);
    float4*   coarse4 = (float4*)(ws + 3276800);
    double*   bs      = (double*)(ws + 3293184);
    unsigned* counter = (unsigned*)(ws + 3318272);

    prep<<<dim3(64), TPB, 0, stream>>>(src_coarse, src_fine, tgt,
                                       fine4, tgt4, coarse4, counter);
    pairmin_all<<<dim3(832), TPB, 0, stream>>>(
        src_coarse, src_fine, tgt, fine4, tgt4, coarse4, pfr, pfc, pcr, pcc);
    tail_all<<<dim3(TAIL_BLOCKS), TPB, 0, stream>>>(
        src_fine, tgt, pfr, pfc, pcr, pcc, bs, counter, out);
}

// Round 6
// 132.848 us; speedup vs baseline: 1.0160x; 1.0160x over previous
//
#include <hip/hip_runtime.h>
#include <stdint.h>
#include <float.h>

using u64 = unsigned long long;
typedef float v2f __attribute__((ext_vector_type(2)));

constexpr int B_ = 2;
constexpr int NC = 512;
constexpr int NF = 8192;
constexpr int MT = 8192;

constexpr int TPB = 256;
constexpr int CF  = 16;            // j-chunks for fine passes & coarse-rows (512 j each)
constexpr int TAIL_BLOCKS = 196;   // 64 + 64 + 4 + 64

#define DEVINL __device__ __forceinline__

// Packed fp32 ops (CDNA packed-math). Each is two correctly-rounded scalar
// fp32 ops — bit-identical to v_mul_f32/v_add_f32 per half. "s" operands are
// SGPR pairs fed straight from uniform s_loads of the pair-interleaved Q.
DEVINL v2f pk_mul_vs(v2f a, v2f b){ v2f d; asm("v_pk_mul_f32 %0, %1, %2" : "=v"(d) : "v"(a), "s"(b)); return d; }
DEVINL v2f pk_add_vv(v2f a, v2f b){ v2f d; asm("v_pk_add_f32 %0, %1, %2" : "=v"(d) : "v"(a), "v"(b)); return d; }
DEVINL v2f pk_add_vs(v2f a, v2f b){ v2f d; asm("v_pk_add_f32 %0, %1, %2" : "=v"(d) : "v"(a), "s"(b)); return d; }

// ---------------------------------------------------------------------------
// prep: pair-interleaved Q layout {x_2p, x_2p+1, y_2p, y_2p+1, z_2p, z_2p+1,
// w_2p, w_2p+1} (w = (x*x+y*y)+z*z, contract off — bit-exact numpy), so
// pairmin's block-uniform 32B reads land in SGPR pairs. Also zeroes counter.
// ---------------------------------------------------------------------------
__global__ __launch_bounds__(TPB) void prep(
    const float* __restrict__ coarse, const float* __restrict__ fine,
    const float* __restrict__ tgt,
    float* __restrict__ finep, float* __restrict__ tgtp,
    float* __restrict__ coarsep, unsigned* __restrict__ counter)
{
#pragma clang fp contract(off)
    int g = blockIdx.x * TPB + threadIdx.x;      // pair index
    if (g == 0) *counter = 0;
    if (g < B_ * NF / 2) {
        {
            const float* p = fine + (size_t)g * 6;
            float x0=p[0],y0=p[1],z0=p[2],x1=p[3],y1=p[4],z1=p[5];
            float* o = finep + (size_t)g * 8;
            o[0]=x0; o[1]=x1; o[2]=y0; o[3]=y1; o[4]=z0; o[5]=z1;
            o[6]=(x0*x0+y0*y0)+z0*z0;  o[7]=(x1*x1+y1*y1)+z1*z1;
        }
        {
            const float* p = tgt + (size_t)g * 6;
            float x0=p[0],y0=p[1],z0=p[2],x1=p[3],y1=p[4],z1=p[5];
            float* o = tgtp + (size_t)g * 8;
            o[0]=x0; o[1]=x1; o[2]=y0; o[3]=y1; o[4]=z0; o[5]=z1;
            o[6]=(x0*x0+y0*y0)+z0*z0;  o[7]=(x1*x1+y1*y1)+z1*z1;
        }
        if (g < B_ * NC / 2) {
            const float* p = coarse + (size_t)g * 6;
            float x0=p[0],y0=p[1],z0=p[2],x1=p[3],y1=p[4],z1=p[5];
            float* o = coarsep + (size_t)g * 8;
            o[0]=x0; o[1]=x1; o[2]=y0; o[3]=y1; o[4]=z0; o[5]=z1;
            o[6]=(x0*x0+y0*y0)+z0*z0;  o[7]=(x1*x1+y1*y1)+z1*z1;
        }
    }
}

// ---------------------------------------------------------------------------
// pairmin: 256 rows (1/thread) vs 256 j-PAIRS. Bit-exact numpy per pair:
//   d = (xx (+) qq) (+) (((-2x0)q0 (+) (-2x1)q1) (+) (-2x2)q2)
// (pre-negated prescale: x2 scaling and negation both commute with RN, so
// this equals (xx+qq) - 2*((x0q0+x1q1)+x2q2) bitwise — verified absmax 0.0
// lineage R1-R5). v_pk ops compute both j's of a pair per instruction.
// ---------------------------------------------------------------------------
template<bool ARGMIN>
DEVINL void pairmin_body(const float* __restrict__ P, const v2f* __restrict__ Qp,
                         int nP, int nQpairsB, int b, int row_base,
                         int jp0, int jplen, int chunk, int nRowsTot,
                         u64* __restrict__ outPack, unsigned* __restrict__ outVal)
{
#pragma clang fp contract(off)
    const int tid = threadIdx.x;
    const int row = row_base + tid;
    const float* p = P + ((size_t)b * nP + row) * 3;
    float a0 = p[0], a1 = p[1], a2 = p[2];
    v2f vax = {-2.0f * a0, -2.0f * a0};
    v2f vay = {-2.0f * a1, -2.0f * a1};
    v2f vaz = {-2.0f * a2, -2.0f * a2};
    float xx = (a0*a0 + a1*a1) + a2*a2;
    v2f vxx = {xx, xx};
    float db0 = FLT_MAX, db1 = FLT_MAX;
    int jb0 = 0, jb1 = 0;

    const v2f* Q = Qp + ((size_t)b * nQpairsB + jp0) * 4;
    v2f qx = Q[0], qy = Q[1], qz = Q[2], qw = Q[3];   // uniform -> s_load
    int j = jp0 * 2;
    for (int k = 0; k < jplen; ++k) {
        const v2f* Qn = Q + (size_t)(k + 1) * 4;      // prefetch next pair
        v2f nx = Qn[0], ny = Qn[1], nz = Qn[2], nw = Qn[3];   // (+32B overrun: padded)
        v2f m0  = pk_mul_vs(vax, qx);
        v2f m1  = pk_mul_vs(vay, qy);
        v2f m2  = pk_mul_vs(vaz, qz);
        v2f s01 = pk_add_vv(m0, m1);
        v2f sxy = pk_add_vv(s01, m2);     // == -(2*xy) bitwise
        v2f tt  = pk_add_vs(vxx, qw);
        v2f d   = pk_add_vv(tt, sxy);     // == (xx+qq) - 2*xy bitwise
        if (ARGMIN) {
            float c0 = fmaxf(d.x, 0.0f);
            float c1 = fmaxf(d.y, 0.0f);
            bool t0 = c0 < db0;  db0 = t0 ? c0 : db0;  jb0 = t0 ? j     : jb0;
            bool t1 = c1 < db1;  db1 = t1 ? c1 : db1;  jb1 = t1 ? (j+1) : jb1;
        } else {
            // med3(d,0,best) == min(best, max(d,0)) for best>=0 — 1 op
            db0 = __builtin_amdgcn_fmed3f(d.x, 0.0f, db0);
            db1 = __builtin_amdgcn_fmed3f(d.y, 0.0f, db1);
        }
        qx = nx; qy = ny; qz = nz; qw = nw;
        j += 2;
    }
    const size_t o = (size_t)chunk * nRowsTot + (size_t)b * nP + row;
    if (ARGMIN) {
        // even/odd chains each track first occurrence in their parity class;
        // on a value tie the smaller index is the global first occurrence.
        bool odd = (db1 < db0) || (db1 == db0 && jb1 < jb0);
        float db = odd ? db1 : db0;
        int   jb = odd ? jb1 : jb0;
        outPack[o] = ((u64)__float_as_uint(db) << 32) | (unsigned)jb;
    } else {
        outVal[o] = __float_as_uint(fminf(db0, db1));
    }
}

// All four passes, one dispatch, 2176 UNIFORM blocks (256 rows x 512 j each).
//  [0,   1024) fine-cols  : P=tgt,    Q=finep   (16 chunks x 32 yb x 2 b)
//  [1024,2048) fine-rows  : P=fine,   Q=tgtp,   ARGMIN
//  [2048,2112) coarse-rows: P=coarse, Q=tgtp    (16 chunks x 2 yb x 2 b)
//  [2112,2176) coarse-cols: P=tgt,    Q=coarsep (1 chunk x 32 yb x 2 b)
__global__ __launch_bounds__(TPB, 8) void pairmin_all(
    const float* __restrict__ coarse, const float* __restrict__ fine,
    const float* __restrict__ tgt,
    const v2f* __restrict__ finep, const v2f* __restrict__ tgtp,
    const v2f* __restrict__ coarsep,
    u64* __restrict__ pfr, unsigned* __restrict__ pfc,
    unsigned* __restrict__ pcr, unsigned* __restrict__ pcc)
{
    const int bx = blockIdx.x;
    if (bx < 1024) {
        int chunk = bx & 15, yb = (bx >> 4) & 31, b = bx >> 9;
        pairmin_body<false>(tgt, finep, MT, NF/2, b, yb*TPB, chunk*256, 256,
                            chunk, B_*MT, nullptr, pfc);
    } else if (bx < 2048) {
        int i = bx - 1024;
        int chunk = i & 15, yb = (i >> 4) & 31, b = i >> 9;
        pairmin_body<true>(fine, tgtp, NF, MT/2, b, yb*TPB, chunk*256, 256,
                           chunk, B_*NF, pfr, nullptr);
    } else if (bx < 2112) {
        int i = bx - 2048;
        int chunk = i & 15, yb = (i >> 4) & 1, b = i >> 5;
        pairmin_body<false>(coarse, tgtp, NC, MT/2, b, yb*TPB, chunk*256, 256,
                            chunk, B_*NC, nullptr, pcr);
    } else {
        int i = bx - 2112;
        int yb = i & 31, b = i >> 5;
        pairmin_body<false>(tgt, coarsep, MT, NC/2, b, yb*TPB, 0, 256,
                            0, B_*MT, nullptr, pcc);
    }
}

// ---------------------------------------------------------------------------
// tail_all: reduce partials, gather, stats, wedge volumes, final combine.
// Last-arriving block (device-scope counter) does the final combine.
// ---------------------------------------------------------------------------
__global__ __launch_bounds__(TPB) void tail_all(
    const float* __restrict__ fine, const float* __restrict__ tgt,
    const u64* __restrict__ pfr, const unsigned* __restrict__ pfc,
    const unsigned* __restrict__ pcr, const unsigned* __restrict__ pcc,
    double* __restrict__ bs, unsigned* __restrict__ counter,
    float* __restrict__ out)
{
    __shared__ float sp[TPB + 2][3], yp[TPB + 2][3];
    __shared__ double redw[4][9];
    __shared__ double lred[4][13];
    __shared__ int lastflag;
    const int bx = blockIdx.x, tid = threadIdx.x;
    const int wave = tid >> 6, lane = tid & 63;

    double v_s = 0, v_d2f = 0, v_d1c = 0, v_d2c = 0, v_yd2 = 0, v_zs = 0, v_zt = 0;
    double vs = 0, vt = 0;
    int role_b = 0;

    if (bx < 64) {                              // ---- fine-rows ----
        const int base = bx * TPB;
        const int g = base + tid;
        const int b = base >> 13;  role_b = b;
        u64 best = pfr[g];
        #pragma unroll
        for (int c = 1; c < CF; ++c) {
            u64 p = pfr[(size_t)c * (B_ * NF) + g];
            best = p < best ? p : best;
        }
        float d1 = __uint_as_float((unsigned)(best >> 32));
        int idx  = (int)(best & 0xffffffffULL);
        float s = sqrtf(fmaxf(d1, 1e-12f));
        const float* y  = tgt  + ((size_t)b * MT + idx) * 3;
        const float* sr = fine + (size_t)g * 3;
        float y0 = y[0],  y1 = y[1],  y2 = y[2];
        float s0 = sr[0], s1 = sr[1], s2 = sr[2];
        yp[tid][0] = y0; yp[tid][1] = y1; yp[tid][2] = y2;
        sp[tid][0] = s0; sp[tid][1] = s1; sp[tid][2] = s2;
        const int base_b = base & (NF - 1);
        if (tid < 2 && base_b + TPB + tid < NF) {        // halo rows
            int g2 = base + TPB + tid;
            u64 b2 = pfr[g2];
            #pragma unroll
            for (int c = 1; c < CF; ++c) {
                u64 p = pfr[(size_t)c * (B_ * NF) + g2];
                b2 = p < b2 ? p : b2;
            }
            int i2 = (int)(b2 & 0xffffffffULL);
            const float* yh = tgt  + ((size_t)b * MT + i2) * 3;
            const float* sh = fine + (size_t)g2 * 3;
            #pragma unroll
            for (int k = 0; k < 3; ++k) { yp[TPB + tid][k] = yh[k]; sp[TPB + tid][k] = sh[k]; }
        }
        __syncthreads();
        v_s = s;
        float yd = s1 - y1;
        v_yd2 = (double)(yd * yd);
        v_zs  = (double)(s2 * s2);
        v_zt  = (double)(y2 * y2);
        int rb = base_b + tid;
        if (rb <= NF - 3) {          // same f32 exprs as the verified R3 kernel
            {
                const float* a = sp[tid]; const float* c = sp[tid+1]; const float* e = sp[tid+2];
                float c0 = a[1]*c[2] - a[2]*c[1];
                float c1 = a[2]*c[0] - a[0]*c[2];
                float c2 = a[0]*c[1] - a[1]*c[0];
                vs = (double)(c0*e[0] + c1*e[1] + c2*e[2]);
            }
            {
                const float* a = yp[tid]; const float* c = yp[tid+1]; const float* e = yp[tid+2];
                float c0 = a[1]*c[2] - a[2]*c[1];
                float c1 = a[2]*c[0] - a[0]*c[2];
                float c2 = a[0]*c[1] - a[1]*c[0];
                vt = (double)(c0*e[0] + c1*e[1] + c2*e[2]);
            }
        }
    } else if (bx < 128) {                      // ---- fine-cols ----
        const int g = (bx - 64) * TPB + tid;
        unsigned best = pfc[g];
        #pragma unroll
        for (int c = 1; c < CF; ++c) best = min(best, pfc[(size_t)c * (B_ * MT) + g]);
        v_d2f = (double)sqrtf(fmaxf(__uint_as_float(best), 1e-12f));
    } else if (bx < 132) {                      // ---- coarse-rows ----
        const int g = (bx - 128) * TPB + tid;
        unsigned best = pcr[g];
        #pragma unroll
        for (int c = 1; c < 16; ++c) best = min(best, pcr[(size_t)c * (B_ * NC) + g]);
        v_d1c = (double)sqrtf(fmaxf(__uint_as_float(best), 1e-12f));
    } else {                                    // ---- coarse-cols ----
        const int g = (bx - 132) * TPB + tid;
        v_d2c = (double)sqrtf(fmaxf(__uint_as_float(pcc[g]), 1e-12f));
    }

    // block reduce 9 values
    double r9[9] = {v_s, v_d2f, v_d1c, v_d2c, v_yd2, v_zs, v_zt, vs, vt};
    for (int o = 32; o; o >>= 1) {
        #pragma unroll
        for (int k = 0; k < 9; ++k) r9[k] += __shfl_down(r9[k], o);
    }
    if (lane == 0) {
        #pragma unroll
        for (int k = 0; k < 9; ++k) redw[wave][k] = r9[k];
    }
    __syncthreads();
    if (tid == 0) {
        double t9[9];
        #pragma unroll
        for (int k = 0; k < 9; ++k)
            t9[k] = redw[0][k] + redw[1][k] + redw[2][k] + redw[3][k];
        double* o = bs + (size_t)bx * 16;
        #pragma unroll
        for (int k = 0; k < 16; ++k) o[k] = 0.0;
        o[0] = t9[0]; o[1] = t9[1]; o[2] = t9[2]; o[3] = t9[3]; o[4] = t9[4];
        o[5 + role_b]  = t9[5];   // zs
        o[7 + role_b]  = t9[6];   // zt
        o[9 + role_b]  = t9[7];   // vs
        o[11 + role_b] = t9[8];   // vt
        __threadfence();
        unsigned old = atomicAdd(counter, 1u);
        lastflag = (old == TAIL_BLOCKS - 1);
    }
    __syncthreads();
    if (!lastflag) return;

    // ---- final combine (last block only) ----
    __threadfence();
    double c13[13];
    if (tid < TAIL_BLOCKS) {
        const double* p = bs + (size_t)tid * 16;
        #pragma unroll
        for (int k = 0; k < 13; ++k) c13[k] = p[k];
    } else {
        #pragma unroll
        for (int k = 0; k < 13; ++k) c13[k] = 0.0;
    }
    for (int o = 32; o; o >>= 1) {
        #pragma unroll
        for (int k = 0; k < 13; ++k) c13[k] += __shfl_down(c13[k], o);
    }
    if (lane == 0) {
        #pragma unroll
        for (int k = 0; k < 13; ++k) lred[wave][k] = c13[k];
    }
    __syncthreads();
    if (tid == 0) {
        double S[13];
        #pragma unroll
        for (int k = 0; k < 13; ++k)
            S[k] = lred[0][k] + lred[1][k] + lred[2][k] + lred[3][k];
        double m_d1f = S[0] / (double)(B_ * NF);
        double m_d2f = S[1] / (double)(B_ * MT);
        double m_d1c = S[2] / (double)(B_ * NC);
        double m_d2c = S[3] / (double)(B_ * MT);
        double loss_align_fine   = 0.5 * (m_d1f + m_d2f);
        double loss_align_coarse = 0.5 * (m_d1c + m_d2c);
        double loss_ref = S[4] / (double)(B_ * NF);
        double loss_rot = 0.0, loss_geo = 0.0;
        for (int b = 0; b < B_; ++b) {
            double dn = sqrt(S[5 + b]) - sqrt(S[7 + b]);
            loss_rot += dn * dn;
            double dv = (S[9 + b] - S[11 + b]) / 6.0;
            loss_geo += dv * dv;
        }
        loss_rot /= (double)B_;
        loss_geo /= (double)B_;
        out[0] = (float)(loss_rot + loss_ref + loss_align_coarse + loss_align_fine + loss_geo);
    }
}

extern "C" void kernel_launch(void* const* d_in, const int* in_sizes, int n_in,
                              void* d_out, int out_size, void* d_ws, size_t ws_size,
                              hipStream_t stream)
{
    const float* src_coarse = (const float*)d_in[0];
    const float* src_fine   = (const float*)d_in[1];
    const float* tgt        = (const float*)d_in[2];
    float* out = (float*)d_out;
    char*  ws  = (char*)d_ws;

    // ws layout (bytes), everything written before read — no init needed.
    // Prefetch may overrun each Qp array by 32 B; the next region absorbs it.
    //   [0,        2097152)  u64 pfr[16][16384]   fine-rows (d,j) partials
    //   [2097152,  3145728)  u32 pfc[16][16384]   fine-cols value partials
    //   [3145728,  3211264)  u32 pcr[16][1024]    coarse-rows value partials
    //   [3211264,  3276800)  u32 pcc[1][16384]    coarse-cols value partials
    //   [3276800,  3538944)  float finep[8192*8]  pair-interleaved
    //   [3538944,  3801088)  float tgtp[8192*8]
    //   [3801088,  3817472)  float coarsep[512*8]
    //   [3817472,  3842560)  double bs[196][16]   per-tail-block sums
    //   [3842560,  3842564)  u32 counter          (zeroed by prep)
    u64*      pfr     = (u64*)(ws);
    unsigned* pfc     = (unsigned*)(ws + 2097152);
    unsigned* pcr     = (unsigned*)(ws + 3145728);
    unsigned* pcc     = (unsigned*)(ws + 3211264);
    float*    finep   = (float*)(ws + 3276800);
    float*    tgtp    = (float*)(ws + 3538944);
    float*    coarsep = (float*)(ws + 3801088);
    double*   bs      = (double*)(ws + 3817472);
    unsigned* counter = (unsigned*)(ws + 3842560);

    prep<<<dim3(32), TPB, 0, stream>>>(src_coarse, src_fine, tgt,
                                       finep, tgtp, coarsep, counter);
    pairmin_all<<<dim3(2176), TPB, 0, stream>>>(
        src_coarse, src_fine, tgt,
        (const v2f*)finep, (const v2f*)tgtp, (const v2f*)coarsep,
        pfr, pfc, pcr, pcc);
    tail_all<<<dim3(TAIL_BLOCKS), TPB, 0, stream>>>(
        src_fine, tgt, pfr, pfc, pcr, pcc, bs, counter, out);
}